// Round 3
// baseline (332.177 us; speedup 1.0000x reference)
//
#include <hip/hip_runtime.h>
#include <math.h>

// Sizes (hard-coded per reference): B=1, L=256, D=128, H=4, DH=32
// positions P = L*L = 65536; HD = H*DH = 128
#define NPOS 65536

typedef _Float16 f16x8 __attribute__((ext_vector_type(8)));
typedef _Float16 f16x4 __attribute__((ext_vector_type(4)));
typedef float    f32x4 __attribute__((ext_vector_type(4)));

__device__ __forceinline__ unsigned short f16bits(_Float16 h) {
    return __builtin_bit_cast(unsigned short, h);
}

// ---------------------------------------------------------------------------
// Kernel P: transpose W{q,k,v,g} (fp32 [k=128][n=128]) into f16 hi plane only:
// Wt_hi[n_global=512][k=128]. (W-lo dropped round-7: adds <=3e-5 to out,
// halves ln_proj's B LDS traffic + MFMA count.)
// ---------------------------------------------------------------------------
__global__ __launch_bounds__(256) void split_w_kernel(
    const float* __restrict__ Wq, const float* __restrict__ Wk,
    const float* __restrict__ Wv, const float* __restrict__ Wg,
    _Float16* __restrict__ Wt_hi)
{
    int t = blockIdx.x * 256 + threadIdx.x;       // 0..65535
    int ng = t >> 7, kk = t & 127;
    int mat = ng >> 7, n = ng & 127;
    const float* W = (mat == 0) ? Wq : (mat == 1) ? Wk : (mat == 2) ? Wv : Wg;
    Wt_hi[t] = (_Float16)W[kk * 128 + n];
}

// ---------------------------------------------------------------------------
// Kernel A (round-7): LN + split-f16(A-side only) MFMA GEMM.
// Outputs now f16: q as hi/lo planes (scale folded), k/v/g hi-only.
// Round-6 evidence (75us, Mfma 13%, VALU 15%, LDS ~68% busy): B-frag
// ds_read_b128 traffic (hi+lo) dominated. Fixes: single B plane (W-lo
// dropped), 2-barrier/chunk pipeline (prev-chunk store overlaps next B load),
// f16 outputs halve store traffic. LDS 34.8KB -> 4 blocks/CU.
// ---------------------------------------------------------------------------
__global__ __launch_bounds__(256, 4) void ln_proj_kernel(
    const float* __restrict__ pair, const float* __restrict__ ln_w, const float* __restrict__ ln_b,
    const float* __restrict__ Wb, const float* __restrict__ bg,
    const _Float16* __restrict__ Wt_hi,
    _Float16* __restrict__ q_hi, _Float16* __restrict__ q_lo,
    _Float16* __restrict__ k16, _Float16* __restrict__ v16, _Float16* __restrict__ g16,
    float* __restrict__ bias_n)
{
    __shared__ _Float16 xbuf[2][64][136];   // [0]: xh then Bh; [1]: xl then stg(u32[64][68])
    _Float16 (*xh)[136] = xbuf[0];
    _Float16 (*xl)[136] = xbuf[1];

    const int tid = threadIdx.x;
    const int p0  = blockIdx.x * 64;
    const int r   = tid >> 2;          // row 0..63
    const int cb  = (tid & 3) * 32;    // col base (4 threads/row)

    // ---- load 32 pair values (float4) ----
    float xv[32];
    {
        const float4* pr = (const float4*)(pair + (size_t)(p0 + r) * 128 + cb);
        #pragma unroll
        for (int i = 0; i < 8; ++i) {
            float4 t = pr[i];
            xv[i * 4 + 0] = t.x; xv[i * 4 + 1] = t.y;
            xv[i * 4 + 2] = t.z; xv[i * 4 + 3] = t.w;
        }
    }
    // ---- LN stats across the 4 threads of the row ----
    float sum = 0.f, sq = 0.f;
    #pragma unroll
    for (int i = 0; i < 32; ++i) { sum += xv[i]; sq += xv[i] * xv[i]; }
    sum += __shfl_xor(sum, 1); sq += __shfl_xor(sq, 1);
    sum += __shfl_xor(sum, 2); sq += __shfl_xor(sq, 2);
    float mean = sum * (1.f / 128.f);
    float var  = sq * (1.f / 128.f) - mean * mean;
    float rstd = rsqrtf(var + 1e-5f);

    // ---- normalize, split to f16 hi/lo, store to LDS; bias partial dots ----
    float b0 = 0.f, b1 = 0.f, b2 = 0.f, b3 = 0.f;
    #pragma unroll
    for (int i8 = 0; i8 < 4; ++i8) {
        float4 lw0 = *(const float4*)(ln_w + cb + i8 * 8);
        float4 lw1 = *(const float4*)(ln_w + cb + i8 * 8 + 4);
        float4 lb0 = *(const float4*)(ln_b + cb + i8 * 8);
        float4 lb1 = *(const float4*)(ln_b + cb + i8 * 8 + 4);
        float lw[8] = {lw0.x, lw0.y, lw0.z, lw0.w, lw1.x, lw1.y, lw1.z, lw1.w};
        float lb[8] = {lb0.x, lb0.y, lb0.z, lb0.w, lb1.x, lb1.y, lb1.z, lb1.w};
        f16x8 hv, lv;
        #pragma unroll
        for (int j = 0; j < 8; ++j) {
            int i = i8 * 8 + j;
            float xn = (xv[i] - mean) * rstd * lw[j] + lb[j];
            _Float16 h = (_Float16)xn;
            hv[j] = h;
            lv[j] = (_Float16)((xn - (float)h) * 2048.0f);
            float4 wb = *(const float4*)(Wb + (size_t)(cb + i) * 4);
            b0 = fmaf(xn, wb.x, b0); b1 = fmaf(xn, wb.y, b1);
            b2 = fmaf(xn, wb.z, b2); b3 = fmaf(xn, wb.w, b3);
        }
        *(f16x8*)&xh[r][cb + i8 * 8] = hv;
        *(f16x8*)&xl[r][cb + i8 * 8] = lv;
    }
    // reduce bias dots across the 4 threads of the row, store natural layout
    b0 += __shfl_xor(b0, 1); b1 += __shfl_xor(b1, 1);
    b2 += __shfl_xor(b2, 1); b3 += __shfl_xor(b3, 1);
    b0 += __shfl_xor(b0, 2); b1 += __shfl_xor(b1, 2);
    b2 += __shfl_xor(b2, 2); b3 += __shfl_xor(b3, 2);
    if ((tid & 3) == 0) {
        int p = p0 + r;                        // p = j*256 + kpos
        bias_n[0 * NPOS + p] = b0;
        bias_n[1 * NPOS + p] = b1;
        bias_n[2 * NPOS + p] = b2;
        bias_n[3 * NPOS + p] = b3;
    }
    __syncthreads();

    // ---- A fragments -> registers (16 rows per wave, full K=128) ----
    const int w  = tid >> 6, l = tid & 63;
    const int lm = l & 15, lg = l >> 4;
    const int arow = w * 16 + lm;

    f16x8 ahf[4], alf[4];
    #pragma unroll
    for (int kt = 0; kt < 4; ++kt) {
        ahf[kt] = *(const f16x8*)&xh[arow][kt * 32 + lg * 8];
        alf[kt] = *(const f16x8*)&xl[arow][kt * 32 + lg * 8];
    }

    _Float16 (*Bh)[136] = xbuf[0];                 // B chunk (single plane)
    unsigned* stg = (unsigned*)&xbuf[1][0][0];     // u32 [64][68] (hi | lo<<16)

    const float scale = 0.17677669529663687f;      // 1/sqrt(32)

    for (int chunk = 0; chunk < 8; ++chunk) {
        __syncthreads();   // stg(chunk-1) writes visible; Bh frag-reads done

        // issue B-chunk global loads (4 x 16B per thread)
        const _Float16* srch = Wt_hi + (size_t)(chunk * 64) * 128;
        f16x8 breg[4];
        #pragma unroll
        for (int it = 0; it < 4; ++it) {
            int idx = it * 256 + tid;
            breg[it] = *(const f16x8*)(srch + (idx >> 4) * 128 + (idx & 15) * 8);
        }

        // store previous chunk's outputs from stg (overlaps B-load latency)
        if (chunk > 0) {
            const int pm = (chunk - 1) >> 1, pcol = ((chunk - 1) & 1) * 64;
            #pragma unroll
            for (int it = 0; it < 4; ++it) {
                int idx = it * 256 + tid;
                int row = idx >> 4, c4 = (idx & 15) * 4;
                uint4 pk = *(const uint4*)&stg[row * 68 + c4];
                ushort4 hv = make_ushort4((unsigned short)(pk.x & 0xffff),
                                          (unsigned short)(pk.y & 0xffff),
                                          (unsigned short)(pk.z & 0xffff),
                                          (unsigned short)(pk.w & 0xffff));
                size_t off = (size_t)(p0 + row) * 128 + pcol + c4;
                if (pm == 0) {
                    *(ushort4*)(q_hi + off) = hv;
                    ushort4 lv = make_ushort4((unsigned short)(pk.x >> 16),
                                              (unsigned short)(pk.y >> 16),
                                              (unsigned short)(pk.z >> 16),
                                              (unsigned short)(pk.w >> 16));
                    *(ushort4*)(q_lo + off) = lv;
                } else if (pm == 1) *(ushort4*)(k16 + off) = hv;
                else if   (pm == 2) *(ushort4*)(v16 + off) = hv;
                else                *(ushort4*)(g16 + off) = hv;
            }
        }

        // write B chunk to LDS
        #pragma unroll
        for (int it = 0; it < 4; ++it) {
            int idx = it * 256 + tid;
            *(f16x8*)&Bh[idx >> 4][(idx & 15) * 8] = breg[it];
        }
        __syncthreads();   // B ready; stg free for rewrite

        // ---- MFMA: 4 col-tiles x 4 kt x 2 (x-split only) ----
        const int mat = chunk >> 1;
        f32x4 acch[4], accc[4];
        #pragma unroll
        for (int ct = 0; ct < 4; ++ct) {
            acch[ct] = (f32x4){0.f, 0.f, 0.f, 0.f};
            accc[ct] = (f32x4){0.f, 0.f, 0.f, 0.f};
        }
        #pragma unroll
        for (int kt = 0; kt < 4; ++kt) {
            const int koff = kt * 32 + lg * 8;
            #pragma unroll
            for (int ct = 0; ct < 4; ++ct) {
                f16x8 bh = *(const f16x8*)&Bh[ct * 16 + lm][koff];
                acch[ct] = __builtin_amdgcn_mfma_f32_16x16x32_f16(ahf[kt], bh, acch[ct], 0, 0, 0);
                accc[ct] = __builtin_amdgcn_mfma_f32_16x16x32_f16(alf[kt], bh, accc[ct], 0, 0, 0);
            }
        }

        // ---- epilogue math -> stg (packed u32) ----
        const int colhalf = (chunk & 1) * 64;
        #pragma unroll
        for (int ct = 0; ct < 4; ++ct) {
            const int col = ct * 16 + lm;
            float bgv = (mat == 3) ? bg[colhalf + col] : 0.f;
            #pragma unroll
            for (int rr = 0; rr < 4; ++rr) {
                float val = acch[ct][rr] + accc[ct][rr] * (1.0f / 2048.0f);
                if (mat == 0) val *= scale;
                if (mat == 3) val = 1.f / (1.f + __expf(-(val + bgv)));
                _Float16 h = (_Float16)val;
                unsigned pk = f16bits(h);
                if (mat == 0) {
                    _Float16 lo = (_Float16)((val - (float)h) * 2048.0f);
                    pk |= ((unsigned)f16bits(lo)) << 16;
                }
                stg[(w * 16 + lg * 4 + rr) * 68 + col] = pk;
            }
        }
    }

    // ---- final chunk store ----
    __syncthreads();
    {
        #pragma unroll
        for (int it = 0; it < 4; ++it) {
            int idx = it * 256 + tid;
            int row = idx >> 4, c4 = (idx & 15) * 4;
            uint4 pk = *(const uint4*)&stg[row * 68 + c4];
            ushort4 hv = make_ushort4((unsigned short)(pk.x & 0xffff),
                                      (unsigned short)(pk.y & 0xffff),
                                      (unsigned short)(pk.z & 0xffff),
                                      (unsigned short)(pk.w & 0xffff));
            *(ushort4*)(g16 + (size_t)(p0 + row) * 128 + 64 + c4) = hv;
        }
    }
}

// ---------------------------------------------------------------------------
// Kernel B (round-10): S^T-form MFMA flash attention, fused PV, with
// per-wave j-ownership HALVED to kill the spill.
// Round-9 post-mortem: fused jt=4 live-set is ~138 regs (qh/ql 32 + Oacc 32
// + mrow/lrow 8 + kf 16 + vf 16 + pre 8 + s 16 + addr) > the 128 cap of
// (256,4); allocator spilled (VGPR 64, ~200MB scratch traffic, 102us).
// Fix: each wave owns 2 j-tiles (32 rows); grid doubles to 2048 blocks
// (bid = i*8 + h*2 + jhalf). jt-scaled state halves: qh/ql 16, Oacc 16,
// mrow/lrow 4 -> peak live ~104 < 128, no spill. K/V staged twice per
// (i,h) (~+33MB L2-warm reads, negligible). 2048 blocks @ 4/CU = two
// full rounds, no partial tail. LDS unchanged 20.2KB.
// ---------------------------------------------------------------------------
__global__ __launch_bounds__(256, 4) void attn_kernel(
    const _Float16* __restrict__ q_hi, const _Float16* __restrict__ q_lo,
    const _Float16* __restrict__ k16, const _Float16* __restrict__ v16,
    const _Float16* __restrict__ g16, const float* __restrict__ bias_n,
    float* __restrict__ go)
{
    __shared__ _Float16 Khs[64][44];
    __shared__ _Float16 Vts[32][76];     // V^T: [d][kpos_local 0..63]
    __shared__ _Float16 Pb[4][16][76];   // per-wave P, current j-tile only

    const int tid  = threadIdx.x;
    const int w    = tid >> 6;
    const int lane = tid & 63;
    const int lg   = lane >> 4, lm = lane & 15;
    const int bid  = blockIdx.x;
    const int i    = bid >> 3;           // 0..255
    const int h    = (bid >> 1) & 3;     // 0..3
    const int jh   = bid & 1;            // j-half 0/1
    const size_t base = (size_t)i * 256 * 128 + (size_t)h * 32;
    const int j0w = jh * 128 + w * 32;   // this wave's 32 j-rows

    // Q fragments: direct f16x8 loads from pre-split planes
    f16x8 qh[2], ql[2];
    #pragma unroll
    for (int jt = 0; jt < 2; ++jt) {
        size_t off = base + (size_t)(j0w + jt * 16 + lm) * 128 + lg * 8;
        qh[jt] = *(const f16x8*)(q_hi + off);
        ql[jt] = *(const f16x8*)(q_lo + off);
    }

    float Oacc[2][2][4] = {};            // [dt][jt][rr]: O^T (col=j=lm, row=d)
    float mrow[2], lrow[2];
    #pragma unroll
    for (int jt = 0; jt < 2; ++jt) { mrow[jt] = -1e30f; lrow[jt] = 0.f; }

    const int sr  = tid >> 2;            // staging kpos-local 0..63
    const int sc8 = (tid & 3) * 8;       // staging d col (8-wide)

    f16x8 kpre = *(const f16x8*)(k16 + base + (size_t)sr * 128 + sc8);
    f16x8 vpre = *(const f16x8*)(v16 + base + (size_t)sr * 128 + sc8);

    for (int kc = 0; kc < 256; kc += 64) {
        __syncthreads();
        *(f16x8*)&Khs[sr][sc8] = kpre;
        #pragma unroll
        for (int e = 0; e < 8; ++e) Vts[sc8 + e][sr] = vpre[e];
        __syncthreads();
        if (kc + 64 < 256) {             // prefetch next phase
            kpre = *(const f16x8*)(k16 + base + (size_t)(kc + 64 + sr) * 128 + sc8);
            vpre = *(const f16x8*)(v16 + base + (size_t)(kc + 64 + sr) * 128 + sc8);
        }

        // A-operand frags: K rows t*16+lm (kpos), V^T rows dt*16+lm (d)
        f16x8 kf[4];
        #pragma unroll
        for (int t = 0; t < 4; ++t) kf[t] = *(const f16x8*)&Khs[t * 16 + lm][lg * 8];
        f16x8 vf[2][2];
        #pragma unroll
        for (int dt = 0; dt < 2; ++dt)
            #pragma unroll
            for (int ks = 0; ks < 2; ++ks)
                vf[dt][ks] = *(const f16x8*)&Vts[dt * 16 + lm][ks * 32 + lg * 8];

        // ---- per j-tile: S^T, softmax over 16 reg scores, P->LDS, PV ----
        #pragma unroll
        for (int jt = 0; jt < 2; ++jt) {
            const float* bj = bias_n + (size_t)h * NPOS
                            + (size_t)(j0w + jt * 16 + lm) * 256 + kc + lg * 4;
            float s[16];
            #pragma unroll
            for (int t = 0; t < 4; ++t) {
                float4 bv = *(const float4*)(bj + t * 16);
                f32x4 c  = {bv.x, bv.y, bv.z, bv.w};
                f32x4 cl = {0.f, 0.f, 0.f, 0.f};
                c  = __builtin_amdgcn_mfma_f32_16x16x32_f16(kf[t], qh[jt], c,  0, 0, 0);
                cl = __builtin_amdgcn_mfma_f32_16x16x32_f16(kf[t], ql[jt], cl, 0, 0, 0);
                #pragma unroll
                for (int rr = 0; rr < 4; ++rr)
                    s[t * 4 + rr] = c[rr] + cl[rr] * (1.0f / 2048.0f);
            }
            float mx = s[0];
            #pragma unroll
            for (int e = 1; e < 16; ++e) mx = fmaxf(mx, s[e]);
            mx = fmaxf(mx, __shfl_xor(mx, 16));
            mx = fmaxf(mx, __shfl_xor(mx, 32));
            float mn = fmaxf(mrow[jt], mx);
            float alpha = __expf(mrow[jt] - mn);
            mrow[jt] = mn;
            float ps = 0.f;
            #pragma unroll
            for (int e = 0; e < 16; ++e) { s[e] = __expf(s[e] - mn); ps += s[e]; }
            ps += __shfl_xor(ps, 16);
            ps += __shfl_xor(ps, 32);
            lrow[jt] = lrow[jt] * alpha + ps;
            #pragma unroll
            for (int dt = 0; dt < 2; ++dt)
                #pragma unroll
                for (int rr = 0; rr < 4; ++rr) Oacc[dt][jt][rr] *= alpha;

            // P -> per-wave LDS slice (same-wave DS ops are in-order: the
            // f16x8 reads below see all 64 lanes' writes, no barrier)
            #pragma unroll
            for (int t = 0; t < 4; ++t) {
                f16x4 pv;
                #pragma unroll
                for (int rr = 0; rr < 4; ++rr) pv[rr] = (_Float16)s[t * 4 + rr];
                *(f16x4*)&Pb[w][lm][t * 16 + lg * 4] = pv;
            }
            f16x8 pf0 = *(const f16x8*)&Pb[w][lm][lg * 8];
            f16x8 pf1 = *(const f16x8*)&Pb[w][lm][32 + lg * 8];
            #pragma unroll
            for (int dt = 0; dt < 2; ++dt) {
                f32x4 c = {Oacc[dt][jt][0], Oacc[dt][jt][1], Oacc[dt][jt][2], Oacc[dt][jt][3]};
                c = __builtin_amdgcn_mfma_f32_16x16x32_f16(vf[dt][0], pf0, c, 0, 0, 0);
                c = __builtin_amdgcn_mfma_f32_16x16x32_f16(vf[dt][1], pf1, c, 0, 0, 0);
                Oacc[dt][jt][0] = c[0]; Oacc[dt][jt][1] = c[1];
                Oacc[dt][jt][2] = c[2]; Oacc[dt][jt][3] = c[3];
            }
        }
    }

    // ---- epilogue: normalize, gate (f16), store go f32 ----
    #pragma unroll
    for (int jt = 0; jt < 2; ++jt) {
        const int j = j0w + jt * 16 + lm;
        const float inv = 1.0f / lrow[jt];
        #pragma unroll
        for (int dt = 0; dt < 2; ++dt) {
            f16x4 gv4 = *(const f16x4*)(g16 + base + (size_t)j * 128 + dt * 16 + lg * 4);
            float4 ov;
            ov.x = Oacc[dt][jt][0] * inv * (float)gv4[0];
            ov.y = Oacc[dt][jt][1] * inv * (float)gv4[1];
            ov.z = Oacc[dt][jt][2] * inv * (float)gv4[2];
            ov.w = Oacc[dt][jt][3] * inv * (float)gv4[3];
            *(float4*)(go + base + (size_t)j * 128 + dt * 16 + lg * 4) = ov;
        }
    }
}

// ---------------------------------------------------------------------------
// Kernel C: out = go @ Wo + bo.  (unchanged)
// ---------------------------------------------------------------------------
__global__ __launch_bounds__(256) void out_proj_kernel(
    const float* __restrict__ go, const float* __restrict__ Wo, const float* __restrict__ bo,
    float* __restrict__ out)
{
    __shared__ float at[64][140];
    const int tid = threadIdx.x;
    const int p0  = blockIdx.x * 64;

    for (int i = tid; i < 64 * 32; i += 256) {
        int row = i >> 5, c4 = (i & 31) * 4;
        float4 val = *(const float4*)(go + (size_t)(p0 + row) * 128 + c4);
        at[row][c4 + 0] = val.x; at[row][c4 + 1] = val.y;
        at[row][c4 + 2] = val.z; at[row][c4 + 3] = val.w;
    }
    __syncthreads();

    const int ty = tid >> 4, tx = tid & 15;
    float acc[4][8] = {};
    #pragma unroll 2
    for (int kk = 0; kk < 128; ++kk) {
        float4 wA = *(const float4*)(Wo + kk * 128 + tx * 8);
        float4 wB = *(const float4*)(Wo + kk * 128 + tx * 8 + 4);
        #pragma unroll
        for (int rr = 0; rr < 4; ++rr) {
            float av = at[ty * 4 + rr][kk];
            acc[rr][0] = fmaf(av, wA.x, acc[rr][0]);
            acc[rr][1] = fmaf(av, wA.y, acc[rr][1]);
            acc[rr][2] = fmaf(av, wA.z, acc[rr][2]);
            acc[rr][3] = fmaf(av, wA.w, acc[rr][3]);
            acc[rr][4] = fmaf(av, wB.x, acc[rr][4]);
            acc[rr][5] = fmaf(av, wB.y, acc[rr][5]);
            acc[rr][6] = fmaf(av, wB.z, acc[rr][6]);
            acc[rr][7] = fmaf(av, wB.w, acc[rr][7]);
        }
    }
    #pragma unroll
    for (int rr = 0; rr < 4; ++rr) {
        float ov[8];
        #pragma unroll
        for (int c = 0; c < 8; ++c) ov[c] = acc[rr][c] + bo[tx * 8 + c];
        float* outp = out + (size_t)(p0 + ty * 4 + rr) * 128 + tx * 8;
        *(float4*)outp       = *(float4*)ov;
        *(float4*)(outp + 4) = *(float4*)(ov + 4);
    }
}

// ---------------------------------------------------------------------------
extern "C" void kernel_launch(void* const* d_in, const int* in_sizes, int n_in,
                              void* d_out, int out_size, void* d_ws, size_t ws_size,
                              hipStream_t stream) {
    const float* pair = (const float*)d_in[0];
    const float* ln_w = (const float*)d_in[1];
    const float* ln_b = (const float*)d_in[2];
    const float* Wq   = (const float*)d_in[3];
    const float* Wk   = (const float*)d_in[4];
    const float* Wv   = (const float*)d_in[5];
    const float* Wb   = (const float*)d_in[6];
    const float* Wg   = (const float*)d_in[7];
    const float* bg   = (const float*)d_in[8];
    const float* Wo   = (const float*)d_in[9];
    const float* bo   = (const float*)d_in[10];

    // workspace: f16 planes q_hi,q_lo,k,v,g (NPOS*128 each) + go f32 + bias_n
    _Float16* q_hi = (_Float16*)d_ws;
    _Float16* q_lo = q_hi + (size_t)NPOS * 128;
    _Float16* k16  = q_lo + (size_t)NPOS * 128;
    _Float16* v16  = k16 + (size_t)NPOS * 128;
    _Float16* g16  = v16 + (size_t)NPOS * 128;
    float* go      = (float*)(g16 + (size_t)NPOS * 128);
    float* bias_n  = go + (size_t)NPOS * 128;
    float* out     = (float*)d_out;

    // Transient scratch for transposed hi-plane weights: in d_out
    // (out_proj overwrites all of d_out at the end).
    _Float16* Wt_hi = (_Float16*)d_out;

    hipLaunchKernelGGL(split_w_kernel, dim3(256), dim3(256), 0, stream,
                       Wq, Wk, Wv, Wg, Wt_hi);
    hipLaunchKernelGGL(ln_proj_kernel, dim3(1024), dim3(256), 0, stream,
                       pair, ln_w, ln_b, Wb, bg, Wt_hi,
                       q_hi, q_lo, k16, v16, g16, bias_n);
    hipLaunchKernelGGL(attn_kernel, dim3(2048), dim3(256), 0, stream,
                       q_hi, q_lo, k16, v16, g16, bias_n, go);
    hipLaunchKernelGGL(out_proj_kernel, dim3(1024), dim3(256), 0, stream,
                       go, Wo, bo, out);
}

// Round 4
// 278.021 us; speedup vs baseline: 1.1948x; 1.1948x over previous
//
#include <hip/hip_runtime.h>
#include <math.h>

// Sizes (hard-coded per reference): B=1, L=256, D=128, H=4, DH=32
// positions P = L*L = 65536; HD = H*DH = 128
#define NPOS 65536

typedef _Float16 f16x8 __attribute__((ext_vector_type(8)));
typedef _Float16 f16x4 __attribute__((ext_vector_type(4)));
typedef float    f32x4 __attribute__((ext_vector_type(4)));

__device__ __forceinline__ unsigned short f16bits(_Float16 h) {
    return __builtin_bit_cast(unsigned short, h);
}

// ---------------------------------------------------------------------------
// Kernel P: transpose W{q,k,v,g} (fp32 [k=128][n=128]) into f16 hi plane only:
// Wt_hi[n_global=512][k=128]. (W-lo dropped round-7: adds <=3e-5 to out,
// halves ln_proj's B LDS traffic + MFMA count.)
// ---------------------------------------------------------------------------
__global__ __launch_bounds__(256) void split_w_kernel(
    const float* __restrict__ Wq, const float* __restrict__ Wk,
    const float* __restrict__ Wv, const float* __restrict__ Wg,
    _Float16* __restrict__ Wt_hi)
{
    int t = blockIdx.x * 256 + threadIdx.x;       // 0..65535
    int ng = t >> 7, kk = t & 127;
    int mat = ng >> 7, n = ng & 127;
    const float* W = (mat == 0) ? Wq : (mat == 1) ? Wk : (mat == 2) ? Wv : Wg;
    Wt_hi[t] = (_Float16)W[kk * 128 + n];
}

// ---------------------------------------------------------------------------
// Kernel A (round-7): LN + split-f16(A-side only) MFMA GEMM.
// Outputs now f16: q as hi/lo planes (scale folded), k/v/g hi-only.
// Round-6 evidence (75us, Mfma 13%, VALU 15%, LDS ~68% busy): B-frag
// ds_read_b128 traffic (hi+lo) dominated. Fixes: single B plane (W-lo
// dropped), 2-barrier/chunk pipeline (prev-chunk store overlaps next B load),
// f16 outputs halve store traffic. LDS 34.8KB -> 4 blocks/CU.
// ---------------------------------------------------------------------------
__global__ __launch_bounds__(256, 4) void ln_proj_kernel(
    const float* __restrict__ pair, const float* __restrict__ ln_w, const float* __restrict__ ln_b,
    const float* __restrict__ Wb, const float* __restrict__ bg,
    const _Float16* __restrict__ Wt_hi,
    _Float16* __restrict__ q_hi, _Float16* __restrict__ q_lo,
    _Float16* __restrict__ k16, _Float16* __restrict__ v16, _Float16* __restrict__ g16,
    float* __restrict__ bias_n)
{
    __shared__ _Float16 xbuf[2][64][136];   // [0]: xh then Bh; [1]: xl then stg(u32[64][68])
    _Float16 (*xh)[136] = xbuf[0];
    _Float16 (*xl)[136] = xbuf[1];

    const int tid = threadIdx.x;
    const int p0  = blockIdx.x * 64;
    const int r   = tid >> 2;          // row 0..63
    const int cb  = (tid & 3) * 32;    // col base (4 threads/row)

    // ---- load 32 pair values (float4) ----
    float xv[32];
    {
        const float4* pr = (const float4*)(pair + (size_t)(p0 + r) * 128 + cb);
        #pragma unroll
        for (int i = 0; i < 8; ++i) {
            float4 t = pr[i];
            xv[i * 4 + 0] = t.x; xv[i * 4 + 1] = t.y;
            xv[i * 4 + 2] = t.z; xv[i * 4 + 3] = t.w;
        }
    }
    // ---- LN stats across the 4 threads of the row ----
    float sum = 0.f, sq = 0.f;
    #pragma unroll
    for (int i = 0; i < 32; ++i) { sum += xv[i]; sq += xv[i] * xv[i]; }
    sum += __shfl_xor(sum, 1); sq += __shfl_xor(sq, 1);
    sum += __shfl_xor(sum, 2); sq += __shfl_xor(sq, 2);
    float mean = sum * (1.f / 128.f);
    float var  = sq * (1.f / 128.f) - mean * mean;
    float rstd = rsqrtf(var + 1e-5f);

    // ---- normalize, split to f16 hi/lo, store to LDS; bias partial dots ----
    float b0 = 0.f, b1 = 0.f, b2 = 0.f, b3 = 0.f;
    #pragma unroll
    for (int i8 = 0; i8 < 4; ++i8) {
        float4 lw0 = *(const float4*)(ln_w + cb + i8 * 8);
        float4 lw1 = *(const float4*)(ln_w + cb + i8 * 8 + 4);
        float4 lb0 = *(const float4*)(ln_b + cb + i8 * 8);
        float4 lb1 = *(const float4*)(ln_b + cb + i8 * 8 + 4);
        float lw[8] = {lw0.x, lw0.y, lw0.z, lw0.w, lw1.x, lw1.y, lw1.z, lw1.w};
        float lb[8] = {lb0.x, lb0.y, lb0.z, lb0.w, lb1.x, lb1.y, lb1.z, lb1.w};
        f16x8 hv, lv;
        #pragma unroll
        for (int j = 0; j < 8; ++j) {
            int i = i8 * 8 + j;
            float xn = (xv[i] - mean) * rstd * lw[j] + lb[j];
            _Float16 h = (_Float16)xn;
            hv[j] = h;
            lv[j] = (_Float16)((xn - (float)h) * 2048.0f);
            float4 wb = *(const float4*)(Wb + (size_t)(cb + i) * 4);
            b0 = fmaf(xn, wb.x, b0); b1 = fmaf(xn, wb.y, b1);
            b2 = fmaf(xn, wb.z, b2); b3 = fmaf(xn, wb.w, b3);
        }
        *(f16x8*)&xh[r][cb + i8 * 8] = hv;
        *(f16x8*)&xl[r][cb + i8 * 8] = lv;
    }
    // reduce bias dots across the 4 threads of the row, store natural layout
    b0 += __shfl_xor(b0, 1); b1 += __shfl_xor(b1, 1);
    b2 += __shfl_xor(b2, 1); b3 += __shfl_xor(b3, 1);
    b0 += __shfl_xor(b0, 2); b1 += __shfl_xor(b1, 2);
    b2 += __shfl_xor(b2, 2); b3 += __shfl_xor(b3, 2);
    if ((tid & 3) == 0) {
        int p = p0 + r;                        // p = j*256 + kpos
        bias_n[0 * NPOS + p] = b0;
        bias_n[1 * NPOS + p] = b1;
        bias_n[2 * NPOS + p] = b2;
        bias_n[3 * NPOS + p] = b3;
    }
    __syncthreads();

    // ---- A fragments -> registers (16 rows per wave, full K=128) ----
    const int w  = tid >> 6, l = tid & 63;
    const int lm = l & 15, lg = l >> 4;
    const int arow = w * 16 + lm;

    f16x8 ahf[4], alf[4];
    #pragma unroll
    for (int kt = 0; kt < 4; ++kt) {
        ahf[kt] = *(const f16x8*)&xh[arow][kt * 32 + lg * 8];
        alf[kt] = *(const f16x8*)&xl[arow][kt * 32 + lg * 8];
    }

    _Float16 (*Bh)[136] = xbuf[0];                 // B chunk (single plane)
    unsigned* stg = (unsigned*)&xbuf[1][0][0];     // u32 [64][68] (hi | lo<<16)

    const float scale = 0.17677669529663687f;      // 1/sqrt(32)

    for (int chunk = 0; chunk < 8; ++chunk) {
        __syncthreads();   // stg(chunk-1) writes visible; Bh frag-reads done

        // issue B-chunk global loads (4 x 16B per thread)
        const _Float16* srch = Wt_hi + (size_t)(chunk * 64) * 128;
        f16x8 breg[4];
        #pragma unroll
        for (int it = 0; it < 4; ++it) {
            int idx = it * 256 + tid;
            breg[it] = *(const f16x8*)(srch + (idx >> 4) * 128 + (idx & 15) * 8);
        }

        // store previous chunk's outputs from stg (overlaps B-load latency)
        if (chunk > 0) {
            const int pm = (chunk - 1) >> 1, pcol = ((chunk - 1) & 1) * 64;
            #pragma unroll
            for (int it = 0; it < 4; ++it) {
                int idx = it * 256 + tid;
                int row = idx >> 4, c4 = (idx & 15) * 4;
                uint4 pk = *(const uint4*)&stg[row * 68 + c4];
                ushort4 hv = make_ushort4((unsigned short)(pk.x & 0xffff),
                                          (unsigned short)(pk.y & 0xffff),
                                          (unsigned short)(pk.z & 0xffff),
                                          (unsigned short)(pk.w & 0xffff));
                size_t off = (size_t)(p0 + row) * 128 + pcol + c4;
                if (pm == 0) {
                    *(ushort4*)(q_hi + off) = hv;
                    ushort4 lv = make_ushort4((unsigned short)(pk.x >> 16),
                                              (unsigned short)(pk.y >> 16),
                                              (unsigned short)(pk.z >> 16),
                                              (unsigned short)(pk.w >> 16));
                    *(ushort4*)(q_lo + off) = lv;
                } else if (pm == 1) *(ushort4*)(k16 + off) = hv;
                else if   (pm == 2) *(ushort4*)(v16 + off) = hv;
                else                *(ushort4*)(g16 + off) = hv;
            }
        }

        // write B chunk to LDS
        #pragma unroll
        for (int it = 0; it < 4; ++it) {
            int idx = it * 256 + tid;
            *(f16x8*)&Bh[idx >> 4][(idx & 15) * 8] = breg[it];
        }
        __syncthreads();   // B ready; stg free for rewrite

        // ---- MFMA: 4 col-tiles x 4 kt x 2 (x-split only) ----
        const int mat = chunk >> 1;
        f32x4 acch[4], accc[4];
        #pragma unroll
        for (int ct = 0; ct < 4; ++ct) {
            acch[ct] = (f32x4){0.f, 0.f, 0.f, 0.f};
            accc[ct] = (f32x4){0.f, 0.f, 0.f, 0.f};
        }
        #pragma unroll
        for (int kt = 0; kt < 4; ++kt) {
            const int koff = kt * 32 + lg * 8;
            #pragma unroll
            for (int ct = 0; ct < 4; ++ct) {
                f16x8 bh = *(const f16x8*)&Bh[ct * 16 + lm][koff];
                acch[ct] = __builtin_amdgcn_mfma_f32_16x16x32_f16(ahf[kt], bh, acch[ct], 0, 0, 0);
                accc[ct] = __builtin_amdgcn_mfma_f32_16x16x32_f16(alf[kt], bh, accc[ct], 0, 0, 0);
            }
        }

        // ---- epilogue math -> stg (packed u32) ----
        const int colhalf = (chunk & 1) * 64;
        #pragma unroll
        for (int ct = 0; ct < 4; ++ct) {
            const int col = ct * 16 + lm;
            float bgv = (mat == 3) ? bg[colhalf + col] : 0.f;
            #pragma unroll
            for (int rr = 0; rr < 4; ++rr) {
                float val = acch[ct][rr] + accc[ct][rr] * (1.0f / 2048.0f);
                if (mat == 0) val *= scale;
                if (mat == 3) val = 1.f / (1.f + __expf(-(val + bgv)));
                _Float16 h = (_Float16)val;
                unsigned pk = f16bits(h);
                if (mat == 0) {
                    _Float16 lo = (_Float16)((val - (float)h) * 2048.0f);
                    pk |= ((unsigned)f16bits(lo)) << 16;
                }
                stg[(w * 16 + lg * 4 + rr) * 68 + col] = pk;
            }
        }
    }

    // ---- final chunk store ----
    __syncthreads();
    {
        #pragma unroll
        for (int it = 0; it < 4; ++it) {
            int idx = it * 256 + tid;
            int row = idx >> 4, c4 = (idx & 15) * 4;
            uint4 pk = *(const uint4*)&stg[row * 68 + c4];
            ushort4 hv = make_ushort4((unsigned short)(pk.x & 0xffff),
                                      (unsigned short)(pk.y & 0xffff),
                                      (unsigned short)(pk.z & 0xffff),
                                      (unsigned short)(pk.w & 0xffff));
            *(ushort4*)(g16 + (size_t)(p0 + row) * 128 + 64 + c4) = hv;
        }
    }
}

// ---------------------------------------------------------------------------
// Kernel B (round-11): round-7's proven register structure (84 arch VGPRs,
// (256,3), no spill) with LDS halved via 2-phase jt split.
// Rounds 8-10 post-mortem: any attempt to raise the waves-per-EU bound
// spilled — on gfx950's unified VGPR/AGPR file the compiler splits the
// per-wave budget between arch and accum (reported arch VGPR == budget/2
// at every bound tried), so the fused loop's arch demand can't fit under
// (256,4+). This round keeps round-7's exact per-thread state and loop
// bodies; ONLY change: jt processed in two halves of 2 tiles, PV pass
// after each half, so Pb shrinks [4][64][76] -> [4][32][76] (38.9->19.4KB).
// LDS 49.4 -> 29.3KB => 5 blocks/CU (VGPR side allows 6 at 84 regs), all
// 1024 blocks co-resident in ONE round (capacity 1280) — tail eliminated.
// Pb slot write->read->overwrite is same-wave in-order DS (validated on
// HW in rounds 8-10, which were numerically correct).
// ---------------------------------------------------------------------------
__global__ __launch_bounds__(256, 3) void attn_kernel(
    const _Float16* __restrict__ q_hi, const _Float16* __restrict__ q_lo,
    const _Float16* __restrict__ k16, const _Float16* __restrict__ v16,
    const _Float16* __restrict__ g16, const float* __restrict__ bias_n,
    float* __restrict__ go)
{
    __shared__ _Float16 Khs[64][44];
    __shared__ _Float16 Vts[32][76];     // V^T: [d][kpos_local 0..63]
    __shared__ _Float16 Pb[4][32][76];   // per-wave P, 2 j-tiles per phase

    const int tid  = threadIdx.x;
    const int w    = tid >> 6;
    const int lane = tid & 63;
    const int lg   = lane >> 4, lm = lane & 15;
    const int i = blockIdx.x >> 2, h = blockIdx.x & 3;
    const size_t base = (size_t)i * 256 * 128 + (size_t)h * 32;
    const int j0w = w * 64;

    // Q fragments: direct f16x8 loads from pre-split planes
    f16x8 qh[4], ql[4];
    #pragma unroll
    for (int jt = 0; jt < 4; ++jt) {
        size_t off = base + (size_t)(j0w + jt * 16 + lm) * 128 + lg * 8;
        qh[jt] = *(const f16x8*)(q_hi + off);
        ql[jt] = *(const f16x8*)(q_lo + off);
    }

    float Oacc[2][4][4] = {};            // [dt][jt][rr]: O^T (col=j=lm, row=d)
    float mrow[4], lrow[4];
    #pragma unroll
    for (int jt = 0; jt < 4; ++jt) { mrow[jt] = -1e30f; lrow[jt] = 0.f; }

    const int sr  = tid >> 2;            // staging kpos-local 0..63
    const int sc8 = (tid & 3) * 8;       // staging d col (8-wide)

    f16x8 kpre = *(const f16x8*)(k16 + base + (size_t)sr * 128 + sc8);
    f16x8 vpre = *(const f16x8*)(v16 + base + (size_t)sr * 128 + sc8);

    for (int kc = 0; kc < 256; kc += 64) {
        __syncthreads();
        *(f16x8*)&Khs[sr][sc8] = kpre;
        #pragma unroll
        for (int e = 0; e < 8; ++e) Vts[sc8 + e][sr] = vpre[e];
        __syncthreads();
        if (kc + 64 < 256) {             // prefetch next phase
            kpre = *(const f16x8*)(k16 + base + (size_t)(kc + 64 + sr) * 128 + sc8);
            vpre = *(const f16x8*)(v16 + base + (size_t)(kc + 64 + sr) * 128 + sc8);
        }

        // A-operand frags: K rows t*16+lm (kpos), V^T rows dt*16+lm (d)
        f16x8 kf[4];
        #pragma unroll
        for (int t = 0; t < 4; ++t) kf[t] = *(const f16x8*)&Khs[t * 16 + lm][lg * 8];
        f16x8 vf[2][2];
        #pragma unroll
        for (int dt = 0; dt < 2; ++dt)
            #pragma unroll
            for (int ks = 0; ks < 2; ++ks)
                vf[dt][ks] = *(const f16x8*)&Vts[dt * 16 + lm][ks * 32 + lg * 8];

        // ---- two jt-phases: {QK+softmax for 2 tiles -> Pb; PV for 2 tiles} ----
        #pragma unroll
        for (int jh2 = 0; jh2 < 2; ++jh2) {
            #pragma unroll
            for (int t2 = 0; t2 < 2; ++t2) {
                const int jt = jh2 * 2 + t2;
                const float* bj = bias_n + (size_t)h * NPOS
                                + (size_t)(j0w + jt * 16 + lm) * 256 + kc + lg * 4;
                float s[16];
                #pragma unroll
                for (int t = 0; t < 4; ++t) {
                    float4 bv = *(const float4*)(bj + t * 16);
                    f32x4 c  = {bv.x, bv.y, bv.z, bv.w};
                    f32x4 cl = {0.f, 0.f, 0.f, 0.f};
                    c  = __builtin_amdgcn_mfma_f32_16x16x32_f16(kf[t], qh[jt], c,  0, 0, 0);
                    cl = __builtin_amdgcn_mfma_f32_16x16x32_f16(kf[t], ql[jt], cl, 0, 0, 0);
                    #pragma unroll
                    for (int rr = 0; rr < 4; ++rr)
                        s[t * 4 + rr] = c[rr] + cl[rr] * (1.0f / 2048.0f);
                }
                float mx = s[0];
                #pragma unroll
                for (int e = 1; e < 16; ++e) mx = fmaxf(mx, s[e]);
                mx = fmaxf(mx, __shfl_xor(mx, 16));
                mx = fmaxf(mx, __shfl_xor(mx, 32));
                float mn = fmaxf(mrow[jt], mx);
                float alpha = __expf(mrow[jt] - mn);
                mrow[jt] = mn;
                float ps = 0.f;
                #pragma unroll
                for (int e = 0; e < 16; ++e) { s[e] = __expf(s[e] - mn); ps += s[e]; }
                ps += __shfl_xor(ps, 16);
                ps += __shfl_xor(ps, 32);
                lrow[jt] = lrow[jt] * alpha + ps;
                #pragma unroll
                for (int dt = 0; dt < 2; ++dt)
                    #pragma unroll
                    for (int rr = 0; rr < 4; ++rr) Oacc[dt][jt][rr] *= alpha;
                #pragma unroll
                for (int t = 0; t < 4; ++t) {
                    f16x4 pv;
                    #pragma unroll
                    for (int rr = 0; rr < 4; ++rr) pv[rr] = (_Float16)s[t * 4 + rr];
                    *(f16x4*)&Pb[w][t2 * 16 + lm][t * 16 + lg * 4] = pv;
                }
            }

            // ---- O^T += V^T * P^T (per-wave Pb; wave DS in-order, no barrier) ----
            #pragma unroll
            for (int t2 = 0; t2 < 2; ++t2) {
                const int jt = jh2 * 2 + t2;
                f16x8 pf0 = *(const f16x8*)&Pb[w][t2 * 16 + lm][lg * 8];
                f16x8 pf1 = *(const f16x8*)&Pb[w][t2 * 16 + lm][32 + lg * 8];
                #pragma unroll
                for (int dt = 0; dt < 2; ++dt) {
                    f32x4 c = {Oacc[dt][jt][0], Oacc[dt][jt][1], Oacc[dt][jt][2], Oacc[dt][jt][3]};
                    c = __builtin_amdgcn_mfma_f32_16x16x32_f16(vf[dt][0], pf0, c, 0, 0, 0);
                    c = __builtin_amdgcn_mfma_f32_16x16x32_f16(vf[dt][1], pf1, c, 0, 0, 0);
                    Oacc[dt][jt][0] = c[0]; Oacc[dt][jt][1] = c[1];
                    Oacc[dt][jt][2] = c[2]; Oacc[dt][jt][3] = c[3];
                }
            }
        }
    }

    // ---- epilogue: normalize, gate (f16), store go f32 ----
    #pragma unroll
    for (int jt = 0; jt < 4; ++jt) {
        const int j = j0w + jt * 16 + lm;
        const float inv = 1.0f / lrow[jt];
        #pragma unroll
        for (int dt = 0; dt < 2; ++dt) {
            f16x4 gv4 = *(const f16x4*)(g16 + base + (size_t)j * 128 + dt * 16 + lg * 4);
            float4 ov;
            ov.x = Oacc[dt][jt][0] * inv * (float)gv4[0];
            ov.y = Oacc[dt][jt][1] * inv * (float)gv4[1];
            ov.z = Oacc[dt][jt][2] * inv * (float)gv4[2];
            ov.w = Oacc[dt][jt][3] * inv * (float)gv4[3];
            *(float4*)(go + base + (size_t)j * 128 + dt * 16 + lg * 4) = ov;
        }
    }
}

// ---------------------------------------------------------------------------
// Kernel C: out = go @ Wo + bo.  (unchanged)
// ---------------------------------------------------------------------------
__global__ __launch_bounds__(256) void out_proj_kernel(
    const float* __restrict__ go, const float* __restrict__ Wo, const float* __restrict__ bo,
    float* __restrict__ out)
{
    __shared__ float at[64][140];
    const int tid = threadIdx.x;
    const int p0  = blockIdx.x * 64;

    for (int i = tid; i < 64 * 32; i += 256) {
        int row = i >> 5, c4 = (i & 31) * 4;
        float4 val = *(const float4*)(go + (size_t)(p0 + row) * 128 + c4);
        at[row][c4 + 0] = val.x; at[row][c4 + 1] = val.y;
        at[row][c4 + 2] = val.z; at[row][c4 + 3] = val.w;
    }
    __syncthreads();

    const int ty = tid >> 4, tx = tid & 15;
    float acc[4][8] = {};
    #pragma unroll 2
    for (int kk = 0; kk < 128; ++kk) {
        float4 wA = *(const float4*)(Wo + kk * 128 + tx * 8);
        float4 wB = *(const float4*)(Wo + kk * 128 + tx * 8 + 4);
        #pragma unroll
        for (int rr = 0; rr < 4; ++rr) {
            float av = at[ty * 4 + rr][kk];
            acc[rr][0] = fmaf(av, wA.x, acc[rr][0]);
            acc[rr][1] = fmaf(av, wA.y, acc[rr][1]);
            acc[rr][2] = fmaf(av, wA.z, acc[rr][2]);
            acc[rr][3] = fmaf(av, wA.w, acc[rr][3]);
            acc[rr][4] = fmaf(av, wB.x, acc[rr][4]);
            acc[rr][5] = fmaf(av, wB.y, acc[rr][5]);
            acc[rr][6] = fmaf(av, wB.z, acc[rr][6]);
            acc[rr][7] = fmaf(av, wB.w, acc[rr][7]);
        }
    }
    #pragma unroll
    for (int rr = 0; rr < 4; ++rr) {
        float ov[8];
        #pragma unroll
        for (int c = 0; c < 8; ++c) ov[c] = acc[rr][c] + bo[tx * 8 + c];
        float* outp = out + (size_t)(p0 + ty * 4 + rr) * 128 + tx * 8;
        *(float4*)outp       = *(float4*)ov;
        *(float4*)(outp + 4) = *(float4*)(ov + 4);
    }
}

// ---------------------------------------------------------------------------
extern "C" void kernel_launch(void* const* d_in, const int* in_sizes, int n_in,
                              void* d_out, int out_size, void* d_ws, size_t ws_size,
                              hipStream_t stream) {
    const float* pair = (const float*)d_in[0];
    const float* ln_w = (const float*)d_in[1];
    const float* ln_b = (const float*)d_in[2];
    const float* Wq   = (const float*)d_in[3];
    const float* Wk   = (const float*)d_in[4];
    const float* Wv   = (const float*)d_in[5];
    const float* Wb   = (const float*)d_in[6];
    const float* Wg   = (const float*)d_in[7];
    const float* bg   = (const float*)d_in[8];
    const float* Wo   = (const float*)d_in[9];
    const float* bo   = (const float*)d_in[10];

    // workspace: f16 planes q_hi,q_lo,k,v,g (NPOS*128 each) + go f32 + bias_n
    _Float16* q_hi = (_Float16*)d_ws;
    _Float16* q_lo = q_hi + (size_t)NPOS * 128;
    _Float16* k16  = q_lo + (size_t)NPOS * 128;
    _Float16* v16  = k16 + (size_t)NPOS * 128;
    _Float16* g16  = v16 + (size_t)NPOS * 128;
    float* go      = (float*)(g16 + (size_t)NPOS * 128);
    float* bias_n  = go + (size_t)NPOS * 128;
    float* out     = (float*)d_out;

    // Transient scratch for transposed hi-plane weights: in d_out
    // (out_proj overwrites all of d_out at the end).
    _Float16* Wt_hi = (_Float16*)d_out;

    hipLaunchKernelGGL(split_w_kernel, dim3(256), dim3(256), 0, stream,
                       Wq, Wk, Wv, Wg, Wt_hi);
    hipLaunchKernelGGL(ln_proj_kernel, dim3(1024), dim3(256), 0, stream,
                       pair, ln_w, ln_b, Wb, bg, Wt_hi,
                       q_hi, q_lo, k16, v16, g16, bias_n);
    hipLaunchKernelGGL(attn_kernel, dim3(1024), dim3(256), 0, stream,
                       q_hi, q_lo, k16, v16, g16, bias_n, go);
    hipLaunchKernelGGL(out_proj_kernel, dim3(1024), dim3(256), 0, stream,
                       go, Wo, bo, out);
}

// Round 5
// 248.316 us; speedup vs baseline: 1.3377x; 1.1196x over previous
//
#include <hip/hip_runtime.h>
#include <math.h>

// Sizes (hard-coded per reference): B=1, L=256, D=128, H=4, DH=32
// positions P = L*L = 65536; HD = H*DH = 128
#define NPOS 65536

typedef _Float16 f16x8 __attribute__((ext_vector_type(8)));
typedef _Float16 f16x4 __attribute__((ext_vector_type(4)));
typedef float    f32x4 __attribute__((ext_vector_type(4)));

__device__ __forceinline__ unsigned short f16bits(_Float16 h) {
    return __builtin_bit_cast(unsigned short, h);
}

// ---------------------------------------------------------------------------
// Kernel P: transpose W{q,k,v,g} (fp32 [k=128][n=128]) into f16 hi plane only:
// Wt_hi[n_global=512][k=128]. Round-12: also emits WoT_hi[n=128][k=128]
// (f16 hi of Wo^T) for the MFMA out_proj. Grid 320 blocks.
// ---------------------------------------------------------------------------
__global__ __launch_bounds__(256) void split_w_kernel(
    const float* __restrict__ Wq, const float* __restrict__ Wk,
    const float* __restrict__ Wv, const float* __restrict__ Wg,
    const float* __restrict__ Wo,
    _Float16* __restrict__ Wt_hi, _Float16* __restrict__ WoT_hi)
{
    int t = blockIdx.x * 256 + threadIdx.x;       // 0..81919
    if (t < 65536) {
        int ng = t >> 7, kk = t & 127;
        int mat = ng >> 7, n = ng & 127;
        const float* W = (mat == 0) ? Wq : (mat == 1) ? Wk : (mat == 2) ? Wv : Wg;
        Wt_hi[t] = (_Float16)W[kk * 128 + n];
    } else {
        int tt = t - 65536;                       // 0..16383
        int n = tt >> 7, kk = tt & 127;
        WoT_hi[tt] = (_Float16)Wo[kk * 128 + n];
    }
}

// ---------------------------------------------------------------------------
// Kernel A (round-7): LN + split-f16(A-side only) MFMA GEMM.  (unchanged)
// ---------------------------------------------------------------------------
__global__ __launch_bounds__(256, 4) void ln_proj_kernel(
    const float* __restrict__ pair, const float* __restrict__ ln_w, const float* __restrict__ ln_b,
    const float* __restrict__ Wb, const float* __restrict__ bg,
    const _Float16* __restrict__ Wt_hi,
    _Float16* __restrict__ q_hi, _Float16* __restrict__ q_lo,
    _Float16* __restrict__ k16, _Float16* __restrict__ v16, _Float16* __restrict__ g16,
    float* __restrict__ bias_n)
{
    __shared__ _Float16 xbuf[2][64][136];   // [0]: xh then Bh; [1]: xl then stg(u32[64][68])
    _Float16 (*xh)[136] = xbuf[0];
    _Float16 (*xl)[136] = xbuf[1];

    const int tid = threadIdx.x;
    const int p0  = blockIdx.x * 64;
    const int r   = tid >> 2;          // row 0..63
    const int cb  = (tid & 3) * 32;    // col base (4 threads/row)

    // ---- load 32 pair values (float4) ----
    float xv[32];
    {
        const float4* pr = (const float4*)(pair + (size_t)(p0 + r) * 128 + cb);
        #pragma unroll
        for (int i = 0; i < 8; ++i) {
            float4 t = pr[i];
            xv[i * 4 + 0] = t.x; xv[i * 4 + 1] = t.y;
            xv[i * 4 + 2] = t.z; xv[i * 4 + 3] = t.w;
        }
    }
    // ---- LN stats across the 4 threads of the row ----
    float sum = 0.f, sq = 0.f;
    #pragma unroll
    for (int i = 0; i < 32; ++i) { sum += xv[i]; sq += xv[i] * xv[i]; }
    sum += __shfl_xor(sum, 1); sq += __shfl_xor(sq, 1);
    sum += __shfl_xor(sum, 2); sq += __shfl_xor(sq, 2);
    float mean = sum * (1.f / 128.f);
    float var  = sq * (1.f / 128.f) - mean * mean;
    float rstd = rsqrtf(var + 1e-5f);

    // ---- normalize, split to f16 hi/lo, store to LDS; bias partial dots ----
    float b0 = 0.f, b1 = 0.f, b2 = 0.f, b3 = 0.f;
    #pragma unroll
    for (int i8 = 0; i8 < 4; ++i8) {
        float4 lw0 = *(const float4*)(ln_w + cb + i8 * 8);
        float4 lw1 = *(const float4*)(ln_w + cb + i8 * 8 + 4);
        float4 lb0 = *(const float4*)(ln_b + cb + i8 * 8);
        float4 lb1 = *(const float4*)(ln_b + cb + i8 * 8 + 4);
        float lw[8] = {lw0.x, lw0.y, lw0.z, lw0.w, lw1.x, lw1.y, lw1.z, lw1.w};
        float lb[8] = {lb0.x, lb0.y, lb0.z, lb0.w, lb1.x, lb1.y, lb1.z, lb1.w};
        f16x8 hv, lv;
        #pragma unroll
        for (int j = 0; j < 8; ++j) {
            int i = i8 * 8 + j;
            float xn = (xv[i] - mean) * rstd * lw[j] + lb[j];
            _Float16 h = (_Float16)xn;
            hv[j] = h;
            lv[j] = (_Float16)((xn - (float)h) * 2048.0f);
            float4 wb = *(const float4*)(Wb + (size_t)(cb + i) * 4);
            b0 = fmaf(xn, wb.x, b0); b1 = fmaf(xn, wb.y, b1);
            b2 = fmaf(xn, wb.z, b2); b3 = fmaf(xn, wb.w, b3);
        }
        *(f16x8*)&xh[r][cb + i8 * 8] = hv;
        *(f16x8*)&xl[r][cb + i8 * 8] = lv;
    }
    // reduce bias dots across the 4 threads of the row, store natural layout
    b0 += __shfl_xor(b0, 1); b1 += __shfl_xor(b1, 1);
    b2 += __shfl_xor(b2, 1); b3 += __shfl_xor(b3, 1);
    b0 += __shfl_xor(b0, 2); b1 += __shfl_xor(b1, 2);
    b2 += __shfl_xor(b2, 2); b3 += __shfl_xor(b3, 2);
    if ((tid & 3) == 0) {
        int p = p0 + r;                        // p = j*256 + kpos
        bias_n[0 * NPOS + p] = b0;
        bias_n[1 * NPOS + p] = b1;
        bias_n[2 * NPOS + p] = b2;
        bias_n[3 * NPOS + p] = b3;
    }
    __syncthreads();

    // ---- A fragments -> registers (16 rows per wave, full K=128) ----
    const int w  = tid >> 6, l = tid & 63;
    const int lm = l & 15, lg = l >> 4;
    const int arow = w * 16 + lm;

    f16x8 ahf[4], alf[4];
    #pragma unroll
    for (int kt = 0; kt < 4; ++kt) {
        ahf[kt] = *(const f16x8*)&xh[arow][kt * 32 + lg * 8];
        alf[kt] = *(const f16x8*)&xl[arow][kt * 32 + lg * 8];
    }

    _Float16 (*Bh)[136] = xbuf[0];                 // B chunk (single plane)
    unsigned* stg = (unsigned*)&xbuf[1][0][0];     // u32 [64][68] (hi | lo<<16)

    const float scale = 0.17677669529663687f;      // 1/sqrt(32)

    for (int chunk = 0; chunk < 8; ++chunk) {
        __syncthreads();   // stg(chunk-1) writes visible; Bh frag-reads done

        // issue B-chunk global loads (4 x 16B per thread)
        const _Float16* srch = Wt_hi + (size_t)(chunk * 64) * 128;
        f16x8 breg[4];
        #pragma unroll
        for (int it = 0; it < 4; ++it) {
            int idx = it * 256 + tid;
            breg[it] = *(const f16x8*)(srch + (idx >> 4) * 128 + (idx & 15) * 8);
        }

        // store previous chunk's outputs from stg (overlaps B-load latency)
        if (chunk > 0) {
            const int pm = (chunk - 1) >> 1, pcol = ((chunk - 1) & 1) * 64;
            #pragma unroll
            for (int it = 0; it < 4; ++it) {
                int idx = it * 256 + tid;
                int row = idx >> 4, c4 = (idx & 15) * 4;
                uint4 pk = *(const uint4*)&stg[row * 68 + c4];
                ushort4 hv = make_ushort4((unsigned short)(pk.x & 0xffff),
                                          (unsigned short)(pk.y & 0xffff),
                                          (unsigned short)(pk.z & 0xffff),
                                          (unsigned short)(pk.w & 0xffff));
                size_t off = (size_t)(p0 + row) * 128 + pcol + c4;
                if (pm == 0) {
                    *(ushort4*)(q_hi + off) = hv;
                    ushort4 lv = make_ushort4((unsigned short)(pk.x >> 16),
                                              (unsigned short)(pk.y >> 16),
                                              (unsigned short)(pk.z >> 16),
                                              (unsigned short)(pk.w >> 16));
                    *(ushort4*)(q_lo + off) = lv;
                } else if (pm == 1) *(ushort4*)(k16 + off) = hv;
                else if   (pm == 2) *(ushort4*)(v16 + off) = hv;
                else                *(ushort4*)(g16 + off) = hv;
            }
        }

        // write B chunk to LDS
        #pragma unroll
        for (int it = 0; it < 4; ++it) {
            int idx = it * 256 + tid;
            *(f16x8*)&Bh[idx >> 4][(idx & 15) * 8] = breg[it];
        }
        __syncthreads();   // B ready; stg free for rewrite

        // ---- MFMA: 4 col-tiles x 4 kt x 2 (x-split only) ----
        const int mat = chunk >> 1;
        f32x4 acch[4], accc[4];
        #pragma unroll
        for (int ct = 0; ct < 4; ++ct) {
            acch[ct] = (f32x4){0.f, 0.f, 0.f, 0.f};
            accc[ct] = (f32x4){0.f, 0.f, 0.f, 0.f};
        }
        #pragma unroll
        for (int kt = 0; kt < 4; ++kt) {
            const int koff = kt * 32 + lg * 8;
            #pragma unroll
            for (int ct = 0; ct < 4; ++ct) {
                f16x8 bh = *(const f16x8*)&Bh[ct * 16 + lm][koff];
                acch[ct] = __builtin_amdgcn_mfma_f32_16x16x32_f16(ahf[kt], bh, acch[ct], 0, 0, 0);
                accc[ct] = __builtin_amdgcn_mfma_f32_16x16x32_f16(alf[kt], bh, accc[ct], 0, 0, 0);
            }
        }

        // ---- epilogue math -> stg (packed u32) ----
        const int colhalf = (chunk & 1) * 64;
        #pragma unroll
        for (int ct = 0; ct < 4; ++ct) {
            const int col = ct * 16 + lm;
            float bgv = (mat == 3) ? bg[colhalf + col] : 0.f;
            #pragma unroll
            for (int rr = 0; rr < 4; ++rr) {
                float val = acch[ct][rr] + accc[ct][rr] * (1.0f / 2048.0f);
                if (mat == 0) val *= scale;
                if (mat == 3) val = 1.f / (1.f + __expf(-(val + bgv)));
                _Float16 h = (_Float16)val;
                unsigned pk = f16bits(h);
                if (mat == 0) {
                    _Float16 lo = (_Float16)((val - (float)h) * 2048.0f);
                    pk |= ((unsigned)f16bits(lo)) << 16;
                }
                stg[(w * 16 + lg * 4 + rr) * 68 + col] = pk;
            }
        }
    }

    // ---- final chunk store ----
    __syncthreads();
    {
        #pragma unroll
        for (int it = 0; it < 4; ++it) {
            int idx = it * 256 + tid;
            int row = idx >> 4, c4 = (idx & 15) * 4;
            uint4 pk = *(const uint4*)&stg[row * 68 + c4];
            ushort4 hv = make_ushort4((unsigned short)(pk.x & 0xffff),
                                      (unsigned short)(pk.y & 0xffff),
                                      (unsigned short)(pk.z & 0xffff),
                                      (unsigned short)(pk.w & 0xffff));
            *(ushort4*)(g16 + (size_t)(p0 + row) * 128 + 64 + c4) = hv;
        }
    }
}

// ---------------------------------------------------------------------------
// Kernel B (round-11): S^T-form MFMA flash attention.  (unchanged from
// round-11: 84 arch VGPRs, no spill, 30.2KB LDS, 94us steady.)
// Round-4 post-mortem: occupancy is register-budget-capped at ~3 waves/SIMD
// (unified VGPR/AGPR file: compiler splits ~170/wave budget arch+accum);
// LDS shrink gave no occupancy gain. Structure is at its register ceiling.
// ---------------------------------------------------------------------------
__global__ __launch_bounds__(256, 3) void attn_kernel(
    const _Float16* __restrict__ q_hi, const _Float16* __restrict__ q_lo,
    const _Float16* __restrict__ k16, const _Float16* __restrict__ v16,
    const _Float16* __restrict__ g16, const float* __restrict__ bias_n,
    float* __restrict__ go)
{
    __shared__ _Float16 Khs[64][44];
    __shared__ _Float16 Vts[32][76];     // V^T: [d][kpos_local 0..63]
    __shared__ _Float16 Pb[4][32][76];   // per-wave P, 2 j-tiles per phase

    const int tid  = threadIdx.x;
    const int w    = tid >> 6;
    const int lane = tid & 63;
    const int lg   = lane >> 4, lm = lane & 15;
    const int i = blockIdx.x >> 2, h = blockIdx.x & 3;
    const size_t base = (size_t)i * 256 * 128 + (size_t)h * 32;
    const int j0w = w * 64;

    // Q fragments: direct f16x8 loads from pre-split planes
    f16x8 qh[4], ql[4];
    #pragma unroll
    for (int jt = 0; jt < 4; ++jt) {
        size_t off = base + (size_t)(j0w + jt * 16 + lm) * 128 + lg * 8;
        qh[jt] = *(const f16x8*)(q_hi + off);
        ql[jt] = *(const f16x8*)(q_lo + off);
    }

    float Oacc[2][4][4] = {};            // [dt][jt][rr]: O^T (col=j=lm, row=d)
    float mrow[4], lrow[4];
    #pragma unroll
    for (int jt = 0; jt < 4; ++jt) { mrow[jt] = -1e30f; lrow[jt] = 0.f; }

    const int sr  = tid >> 2;            // staging kpos-local 0..63
    const int sc8 = (tid & 3) * 8;       // staging d col (8-wide)

    f16x8 kpre = *(const f16x8*)(k16 + base + (size_t)sr * 128 + sc8);
    f16x8 vpre = *(const f16x8*)(v16 + base + (size_t)sr * 128 + sc8);

    for (int kc = 0; kc < 256; kc += 64) {
        __syncthreads();
        *(f16x8*)&Khs[sr][sc8] = kpre;
        #pragma unroll
        for (int e = 0; e < 8; ++e) Vts[sc8 + e][sr] = vpre[e];
        __syncthreads();
        if (kc + 64 < 256) {             // prefetch next phase
            kpre = *(const f16x8*)(k16 + base + (size_t)(kc + 64 + sr) * 128 + sc8);
            vpre = *(const f16x8*)(v16 + base + (size_t)(kc + 64 + sr) * 128 + sc8);
        }

        // A-operand frags: K rows t*16+lm (kpos), V^T rows dt*16+lm (d)
        f16x8 kf[4];
        #pragma unroll
        for (int t = 0; t < 4; ++t) kf[t] = *(const f16x8*)&Khs[t * 16 + lm][lg * 8];
        f16x8 vf[2][2];
        #pragma unroll
        for (int dt = 0; dt < 2; ++dt)
            #pragma unroll
            for (int ks = 0; ks < 2; ++ks)
                vf[dt][ks] = *(const f16x8*)&Vts[dt * 16 + lm][ks * 32 + lg * 8];

        // ---- two jt-phases: {QK+softmax for 2 tiles -> Pb; PV for 2 tiles} ----
        #pragma unroll
        for (int jh2 = 0; jh2 < 2; ++jh2) {
            #pragma unroll
            for (int t2 = 0; t2 < 2; ++t2) {
                const int jt = jh2 * 2 + t2;
                const float* bj = bias_n + (size_t)h * NPOS
                                + (size_t)(j0w + jt * 16 + lm) * 256 + kc + lg * 4;
                float s[16];
                #pragma unroll
                for (int t = 0; t < 4; ++t) {
                    float4 bv = *(const float4*)(bj + t * 16);
                    f32x4 c  = {bv.x, bv.y, bv.z, bv.w};
                    f32x4 cl = {0.f, 0.f, 0.f, 0.f};
                    c  = __builtin_amdgcn_mfma_f32_16x16x32_f16(kf[t], qh[jt], c,  0, 0, 0);
                    cl = __builtin_amdgcn_mfma_f32_16x16x32_f16(kf[t], ql[jt], cl, 0, 0, 0);
                    #pragma unroll
                    for (int rr = 0; rr < 4; ++rr)
                        s[t * 4 + rr] = c[rr] + cl[rr] * (1.0f / 2048.0f);
                }
                float mx = s[0];
                #pragma unroll
                for (int e = 1; e < 16; ++e) mx = fmaxf(mx, s[e]);
                mx = fmaxf(mx, __shfl_xor(mx, 16));
                mx = fmaxf(mx, __shfl_xor(mx, 32));
                float mn = fmaxf(mrow[jt], mx);
                float alpha = __expf(mrow[jt] - mn);
                mrow[jt] = mn;
                float ps = 0.f;
                #pragma unroll
                for (int e = 0; e < 16; ++e) { s[e] = __expf(s[e] - mn); ps += s[e]; }
                ps += __shfl_xor(ps, 16);
                ps += __shfl_xor(ps, 32);
                lrow[jt] = lrow[jt] * alpha + ps;
                #pragma unroll
                for (int dt = 0; dt < 2; ++dt)
                    #pragma unroll
                    for (int rr = 0; rr < 4; ++rr) Oacc[dt][jt][rr] *= alpha;
                #pragma unroll
                for (int t = 0; t < 4; ++t) {
                    f16x4 pv;
                    #pragma unroll
                    for (int rr = 0; rr < 4; ++rr) pv[rr] = (_Float16)s[t * 4 + rr];
                    *(f16x4*)&Pb[w][t2 * 16 + lm][t * 16 + lg * 4] = pv;
                }
            }

            // ---- O^T += V^T * P^T (per-wave Pb; wave DS in-order, no barrier) ----
            #pragma unroll
            for (int t2 = 0; t2 < 2; ++t2) {
                const int jt = jh2 * 2 + t2;
                f16x8 pf0 = *(const f16x8*)&Pb[w][t2 * 16 + lm][lg * 8];
                f16x8 pf1 = *(const f16x8*)&Pb[w][t2 * 16 + lm][32 + lg * 8];
                #pragma unroll
                for (int dt = 0; dt < 2; ++dt) {
                    f32x4 c = {Oacc[dt][jt][0], Oacc[dt][jt][1], Oacc[dt][jt][2], Oacc[dt][jt][3]};
                    c = __builtin_amdgcn_mfma_f32_16x16x32_f16(vf[dt][0], pf0, c, 0, 0, 0);
                    c = __builtin_amdgcn_mfma_f32_16x16x32_f16(vf[dt][1], pf1, c, 0, 0, 0);
                    Oacc[dt][jt][0] = c[0]; Oacc[dt][jt][1] = c[1];
                    Oacc[dt][jt][2] = c[2]; Oacc[dt][jt][3] = c[3];
                }
            }
        }
    }

    // ---- epilogue: normalize, gate (f16), store go f32 ----
    #pragma unroll
    for (int jt = 0; jt < 4; ++jt) {
        const int j = j0w + jt * 16 + lm;
        const float inv = 1.0f / lrow[jt];
        #pragma unroll
        for (int dt = 0; dt < 2; ++dt) {
            f16x4 gv4 = *(const f16x4*)(g16 + base + (size_t)j * 128 + dt * 16 + lg * 4);
            float4 ov;
            ov.x = Oacc[dt][jt][0] * inv * (float)gv4[0];
            ov.y = Oacc[dt][jt][1] * inv * (float)gv4[1];
            ov.z = Oacc[dt][jt][2] * inv * (float)gv4[2];
            ov.w = Oacc[dt][jt][3] * inv * (float)gv4[3];
            *(float4*)(go + base + (size_t)j * 128 + dt * 16 + lg * 4) = ov;
        }
    }
}

// ---------------------------------------------------------------------------
// Kernel C (round-12): out = go @ Wo + bo as MFMA f16 GEMM.
// Previous out_proj was a scalar-fmaf fp32 GEMM (~8200 VALU-cy/wave on the
// vector pipe while MFMA sat idle). This clones ln_proj's PROVEN inner
// structure: A = go split to f16 hi/lo in LDS (on the fly, err ~1e-6),
// B = WoT_hi f16 hi-only (same "W hi-only <=3e-5" pattern as Wq..Wg).
// 2 n-chunks of 64; MFMA 4.3GF ~2us; kernel becomes BW-bound (~66MB).
// LDS 52.2KB -> 3 blocks/CU.
// ---------------------------------------------------------------------------
__global__ __launch_bounds__(256, 3) void out_proj_kernel(
    const float* __restrict__ go, const _Float16* __restrict__ WoT_hi,
    const float* __restrict__ bo, float* __restrict__ out)
{
    __shared__ _Float16 xh[64][136];
    __shared__ _Float16 xl[64][136];
    __shared__ _Float16 Bh[64][136];

    const int tid = threadIdx.x;
    const int p0  = blockIdx.x * 64;
    const int r   = tid >> 2;          // row 0..63
    const int cb  = (tid & 3) * 32;    // col base (4 threads/row)

    // ---- load 32 go values, split hi/lo into LDS ----
    {
        const float4* pr = (const float4*)(go + (size_t)(p0 + r) * 128 + cb);
        #pragma unroll
        for (int i8 = 0; i8 < 4; ++i8) {
            float4 a = pr[i8 * 2], b = pr[i8 * 2 + 1];
            float v[8] = {a.x, a.y, a.z, a.w, b.x, b.y, b.z, b.w};
            f16x8 hv, lv;
            #pragma unroll
            for (int j = 0; j < 8; ++j) {
                _Float16 h = (_Float16)v[j];
                hv[j] = h;
                lv[j] = (_Float16)((v[j] - (float)h) * 2048.0f);
            }
            *(f16x8*)&xh[r][cb + i8 * 8] = hv;
            *(f16x8*)&xl[r][cb + i8 * 8] = lv;
        }
    }
    __syncthreads();

    const int w  = tid >> 6, l = tid & 63;
    const int lm = l & 15, lg = l >> 4;
    const int arow = w * 16 + lm;

    f16x8 ahf[4], alf[4];
    #pragma unroll
    for (int kt = 0; kt < 4; ++kt) {
        ahf[kt] = *(const f16x8*)&xh[arow][kt * 32 + lg * 8];
        alf[kt] = *(const f16x8*)&xl[arow][kt * 32 + lg * 8];
    }

    #pragma unroll
    for (int chunk = 0; chunk < 2; ++chunk) {
        // issue B-chunk global loads (4 x 16B per thread), then sync before
        // overwriting Bh (chunk 1: prior MFMA ds-reads must be done)
        const _Float16* srch = WoT_hi + (size_t)(chunk * 64) * 128;
        f16x8 breg[4];
        #pragma unroll
        for (int it = 0; it < 4; ++it) {
            int idx = it * 256 + tid;
            breg[it] = *(const f16x8*)(srch + (idx >> 4) * 128 + (idx & 15) * 8);
        }
        if (chunk > 0) __syncthreads();
        #pragma unroll
        for (int it = 0; it < 4; ++it) {
            int idx = it * 256 + tid;
            *(f16x8*)&Bh[idx >> 4][(idx & 15) * 8] = breg[it];
        }
        __syncthreads();

        f32x4 acch[4], accc[4];
        #pragma unroll
        for (int ct = 0; ct < 4; ++ct) {
            acch[ct] = (f32x4){0.f, 0.f, 0.f, 0.f};
            accc[ct] = (f32x4){0.f, 0.f, 0.f, 0.f};
        }
        #pragma unroll
        for (int kt = 0; kt < 4; ++kt) {
            const int koff = kt * 32 + lg * 8;
            #pragma unroll
            for (int ct = 0; ct < 4; ++ct) {
                f16x8 bh = *(const f16x8*)&Bh[ct * 16 + lm][koff];
                acch[ct] = __builtin_amdgcn_mfma_f32_16x16x32_f16(ahf[kt], bh, acch[ct], 0, 0, 0);
                accc[ct] = __builtin_amdgcn_mfma_f32_16x16x32_f16(alf[kt], bh, accc[ct], 0, 0, 0);
            }
        }

        // ---- store: out[p0 + w*16 + lg*4 + rr][chunk*64 + ct*16 + lm] ----
        #pragma unroll
        for (int ct = 0; ct < 4; ++ct) {
            const int col = chunk * 64 + ct * 16 + lm;
            const float bov = bo[col];
            #pragma unroll
            for (int rr = 0; rr < 4; ++rr) {
                const int row = p0 + w * 16 + lg * 4 + rr;
                out[(size_t)row * 128 + col] =
                    acch[ct][rr] + accc[ct][rr] * (1.0f / 2048.0f) + bov;
            }
        }
    }
}

// ---------------------------------------------------------------------------
extern "C" void kernel_launch(void* const* d_in, const int* in_sizes, int n_in,
                              void* d_out, int out_size, void* d_ws, size_t ws_size,
                              hipStream_t stream) {
    const float* pair = (const float*)d_in[0];
    const float* ln_w = (const float*)d_in[1];
    const float* ln_b = (const float*)d_in[2];
    const float* Wq   = (const float*)d_in[3];
    const float* Wk   = (const float*)d_in[4];
    const float* Wv   = (const float*)d_in[5];
    const float* Wb   = (const float*)d_in[6];
    const float* Wg   = (const float*)d_in[7];
    const float* bg   = (const float*)d_in[8];
    const float* Wo   = (const float*)d_in[9];
    const float* bo   = (const float*)d_in[10];

    // workspace: f16 planes q_hi,q_lo,k,v,g (NPOS*128 each) + go f32 + bias_n
    // + WoT_hi (128x128 f16)
    _Float16* q_hi = (_Float16*)d_ws;
    _Float16* q_lo = q_hi + (size_t)NPOS * 128;
    _Float16* k16  = q_lo + (size_t)NPOS * 128;
    _Float16* v16  = k16 + (size_t)NPOS * 128;
    _Float16* g16  = v16 + (size_t)NPOS * 128;
    float* go      = (float*)(g16 + (size_t)NPOS * 128);
    float* bias_n  = go + (size_t)NPOS * 128;
    _Float16* WoT_hi = (_Float16*)(bias_n + 4 * (size_t)NPOS);
    float* out     = (float*)d_out;

    // Transient scratch for transposed hi-plane weights: in d_out
    // (out_proj overwrites all of d_out at the end).
    _Float16* Wt_hi = (_Float16*)d_out;

    hipLaunchKernelGGL(split_w_kernel, dim3(320), dim3(256), 0, stream,
                       Wq, Wk, Wv, Wg, Wo, Wt_hi, WoT_hi);
    hipLaunchKernelGGL(ln_proj_kernel, dim3(1024), dim3(256), 0, stream,
                       pair, ln_w, ln_b, Wb, bg, Wt_hi,
                       q_hi, q_lo, k16, v16, g16, bias_n);
    hipLaunchKernelGGL(attn_kernel, dim3(1024), dim3(256), 0, stream,
                       q_hi, q_lo, k16, v16, g16, bias_n, go);
    hipLaunchKernelGGL(out_proj_kernel, dim3(1024), dim3(256), 0, stream,
                       go, WoT_hi, bo, out);
}